// Round 1
// baseline (6115.730 us; speedup 1.0000x reference)
//
#include <hip/hip_runtime.h>
#include <cstdint>

typedef __attribute__((ext_vector_type(4))) float f32x4;
typedef __attribute__((ext_vector_type(8))) short s16x8;
typedef __attribute__((ext_vector_type(8))) unsigned short u16x8;
typedef __attribute__((ext_vector_type(4))) unsigned short u16x4;

#define DEVI __device__ __forceinline__

namespace {

constexpr int B = 32, L = 2048, D = 1024, H = 16;
constexpr int CHUNK = 128, MEM = 64, T = 192;
constexpr int NC = 16;

DEVI unsigned short f2bf(float f) {
  unsigned x = __builtin_bit_cast(unsigned, f);
  return (unsigned short)((x + 0x7fffu + ((x >> 16) & 1u)) >> 16);
}

typedef const __attribute__((address_space(1))) unsigned char ga_t;
typedef __attribute__((address_space(3))) unsigned char la_t;

DEVI void gload16(const void* g, void* l) {
  __builtin_amdgcn_global_load_lds((ga_t*)g, (la_t*)l, 16, 0, 0);
}

__global__ void k_cvt(const float* __restrict__ in, unsigned short* __restrict__ out, int n) {
  int i = blockIdx.x * 256 + threadIdx.x;
  if (i < n) out[i] = f2bf(in[i]);
}

__global__ void k_copy_mem(const float* __restrict__ src, float* __restrict__ dst) {
  int i = blockIdx.x * 256 + threadIdx.x;
  dst[i] = src[i];
}

// MODE 0: build z (mem/emb + pos), write z f32 and LN(z)->bf16
// MODE 1: read z f32, write LN(z)->bf16
template<int MODE>
__global__ __launch_bounds__(256) void k_ln(
    const float* __restrict__ memb, const float* __restrict__ mem_init,
    const float* __restrict__ pos,
    const float* __restrict__ embP, const float* __restrict__ embS,
    const int* __restrict__ ipr, const int* __restrict__ isk,
    const float* __restrict__ gg, const float* __restrict__ bb,
    float* __restrict__ z, unsigned short* __restrict__ lnout, int t)
{
  const int row = blockIdx.x;          // 0 .. B*T-1
  const int b = row / T, i = row % T;
  const int tid = threadIdx.x;
  const int d0 = tid * 4;
  float v[4];
  if constexpr (MODE == 0) {
    if (i < MEM) {
      const float* src = (t == 0) ? (mem_init + (size_t)i * D)
                                  : (memb + ((size_t)b * MEM + i) * D);
      #pragma unroll
      for (int e = 0; e < 4; ++e) v[e] = src[d0 + e] + pos[i * D + d0 + e];
    } else {
      const int j = t * CHUNK + (i - MEM);
      const int pi = ipr[b * L + j], si = isk[b * L + j];
      #pragma unroll
      for (int e = 0; e < 4; ++e)
        v[e] = embP[(size_t)pi * D + d0 + e] + embS[(size_t)si * D + d0 + e] + pos[i * D + d0 + e];
    }
  } else {
    const f32x4 zz = *reinterpret_cast<const f32x4*>(&z[(size_t)row * D + d0]);
    v[0] = zz[0]; v[1] = zz[1]; v[2] = zz[2]; v[3] = zz[3];
  }
  float s  = v[0] + v[1] + v[2] + v[3];
  float s2 = v[0]*v[0] + v[1]*v[1] + v[2]*v[2] + v[3]*v[3];
  #pragma unroll
  for (int m = 1; m < 64; m <<= 1) { s += __shfl_xor(s, m, 64); s2 += __shfl_xor(s2, m, 64); }
  __shared__ float ps[4], ps2[4];
  const int wid = tid >> 6;
  if ((tid & 63) == 0) { ps[wid] = s; ps2[wid] = s2; }
  __syncthreads();
  s  = ps[0] + ps[1] + ps[2] + ps[3];
  s2 = ps2[0] + ps2[1] + ps2[2] + ps2[3];
  const float mu  = s * (1.0f / 1024.0f);
  const float var = s2 * (1.0f / 1024.0f) - mu * mu;
  const float rs  = rsqrtf(var + 1e-5f);
  if constexpr (MODE == 0) {
    f32x4 zz = {v[0], v[1], v[2], v[3]};
    *reinterpret_cast<f32x4*>(&z[(size_t)row * D + d0]) = zz;
  }
  u16x4 o;
  #pragma unroll
  for (int e = 0; e < 4; ++e)
    o[e] = f2bf((v[e] - mu) * rs * gg[d0 + e] + bb[d0 + e]);
  *reinterpret_cast<u16x4*>(&lnout[(size_t)row * D + d0]) = o;
}

struct GArgs {
  const unsigned short* A; const unsigned short* W; const float* bias;
  unsigned short* outb; float* z; float* outf; unsigned short* candb; float* mem;
  int M, N, K, t;
};

// C[M][N] = A[M][K] @ W[N][K]^T + bias, epilogue per EPI.
// EPI 0: bf16 out     1: relu->bf16 out    2: z += v
// EPI 3: zv=z+v; i<MEM -> z & cand_bf16 ; else -> d_out
// EPI 4: gate: mem = (t==0) ? cand : sig(v)*cand + (1-sig(v))*mem
template<int EPI>
__global__ __launch_bounds__(256) void k_gemm(GArgs a)
{
  __shared__ unsigned short Al[128 * 64];
  __shared__ unsigned short Bl[128 * 64];
  const int tid = threadIdx.x;
  const int lane = tid & 63, wid = tid >> 6;
  const int brow = blockIdx.y * 128, bcol = blockIdx.x * 128;
  const int wr = wid >> 1, wc = wid & 1;
  const int lr = lane >> 3, lc8 = (lane & 7) * 8;
  const int c0 = lane & 15, g4 = lane >> 4;

  f32x4 acc[4][4] = {};

  const int nkt = a.K >> 6;
  for (int kt = 0; kt < nkt; ++kt) {
    const int kb = kt * 64;
    #pragma unroll
    for (int q = 0; q < 4; ++q) {
      const int seg = wid * 4 + q;                       // 0..15, 8 rows each
      gload16(&a.A[(size_t)(brow + seg * 8 + lr) * a.K + kb + lc8], &Al[seg * 512]);
      gload16(&a.W[(size_t)(bcol + seg * 8 + lr) * a.K + kb + lc8], &Bl[seg * 512]);
    }
    __syncthreads();   // drains vmcnt -> LDS tiles ready
    #pragma unroll
    for (int kk = 0; kk < 2; ++kk) {
      s16x8 af[4], bf[4];
      #pragma unroll
      for (int m = 0; m < 4; ++m)
        af[m] = *reinterpret_cast<const s16x8*>(&Al[(wr * 64 + m * 16 + c0) * 64 + kk * 32 + g4 * 8]);
      #pragma unroll
      for (int n = 0; n < 4; ++n)
        bf[n] = *reinterpret_cast<const s16x8*>(&Bl[(wc * 64 + n * 16 + c0) * 64 + kk * 32 + g4 * 8]);
      #pragma unroll
      for (int m = 0; m < 4; ++m)
        #pragma unroll
        for (int n = 0; n < 4; ++n)
          acc[m][n] = __builtin_amdgcn_mfma_f32_16x16x32_bf16(af[m], bf[n], acc[m][n], 0, 0, 0);
    }
    __syncthreads();   // protect LDS from next stage
  }

  #pragma unroll
  for (int m = 0; m < 4; ++m) {
    #pragma unroll
    for (int n = 0; n < 4; ++n) {
      const int col = bcol + wc * 64 + n * 16 + c0;
      const float bv = a.bias[col];
      #pragma unroll
      for (int j = 0; j < 4; ++j) {
        const int row = brow + wr * 64 + m * 16 + g4 * 4 + j;
        float v = acc[m][n][j] + bv;
        if constexpr (EPI == 0) {
          a.outb[(size_t)row * a.N + col] = f2bf(v);
        } else if constexpr (EPI == 1) {
          a.outb[(size_t)row * a.N + col] = f2bf(v > 0.f ? v : 0.f);
        } else if constexpr (EPI == 2) {
          a.z[(size_t)row * a.N + col] += v;
        } else if constexpr (EPI == 3) {
          const float zv = a.z[(size_t)row * a.N + col] + v;
          const int bb2 = row / T, ii = row % T;
          if (ii < MEM) {
            a.z[(size_t)row * a.N + col] = zv;
            a.candb[((size_t)bb2 * MEM + ii) * D + col] = f2bf(zv);
          } else {
            a.outf[((size_t)bb2 * L + a.t * CHUNK + (ii - MEM)) * D + col] = zv;
          }
        } else {
          const float g = 1.0f / (1.0f + __expf(-v));
          const int bb2 = row >> 6, ii = row & 63;
          const float cand = a.z[((size_t)bb2 * T + ii) * D + col];
          const float mo = a.mem[(size_t)row * D + col];
          a.mem[(size_t)row * D + col] = (a.t == 0) ? cand : g * cand + (1.0f - g) * mo;
        }
      }
    }
  }
}

// One workgroup per (b,h). qkv: [B*T][3072] bf16 (q|k|v each H*64 cols).
__global__ __launch_bounds__(256) void k_attn(const unsigned short* __restrict__ qkv,
                                              unsigned short* __restrict__ attno)
{
  __shared__ unsigned short Ks[192 * 64];    // K, 8-elem-block XOR swizzle
  __shared__ unsigned short Vt[64 * 192];    // V^T, 8-key-block rotation per hd row
  __shared__ unsigned short Pl[4][16 * 200]; // per-wave P, padded rows
  const int tid = threadIdx.x, lane = tid & 63, wid = tid >> 6;
  const int b = blockIdx.x >> 4, h = blockIdx.x & 15;
  const size_t base = (size_t)b * T * 3072 + h * 64;

  #pragma unroll
  for (int it = 0; it < 6; ++it) {
    const int cidx = tid + it * 256;         // 0..1535 = 192 keys * 8 blocks
    const int key = cidx >> 3, hb = cidx & 7;
    const u16x8 kv = *reinterpret_cast<const u16x8*>(&qkv[base + (size_t)key * 3072 + 1024 + hb * 8]);
    *reinterpret_cast<u16x8*>(&Ks[key * 64 + ((hb ^ (key & 7)) * 8)]) = kv;
    const u16x8 vv = *reinterpret_cast<const u16x8*>(&qkv[base + (size_t)key * 3072 + 2048 + hb * 8]);
    #pragma unroll
    for (int e = 0; e < 8; ++e) {
      const int hd = hb * 8 + e;
      Vt[hd * 192 + (((key >> 3) + hd) % 24) * 8 + (key & 7)] = vv[e];
    }
  }
  __syncthreads();

  const int c0 = lane & 15, g4 = lane >> 4;
  for (int qb = wid; qb < 12; qb += 4) {     // 3 q-blocks per wave
    s16x8 qf[2];
    #pragma unroll
    for (int kk = 0; kk < 2; ++kk)
      qf[kk] = *reinterpret_cast<const s16x8*>(&qkv[base + (size_t)(qb * 16 + c0) * 3072 + kk * 32 + g4 * 8]);
    f32x4 sc[12];
    #pragma unroll
    for (int cb = 0; cb < 12; ++cb) {
      f32x4 s4 = {};
      #pragma unroll
      for (int kk = 0; kk < 2; ++kk) {
        const s16x8 kf = *reinterpret_cast<const s16x8*>(
            &Ks[(cb * 16 + c0) * 64 + (((kk * 4 + g4) ^ (c0 & 7)) * 8)]);
        s4 = __builtin_amdgcn_mfma_f32_16x16x32_bf16(qf[kk], kf, s4, 0, 0, 0);
      }
      sc[cb] = s4;
    }
    // scale + mask + softmax (row q = qb*16 + g4*4 + j, col key = cb*16 + c0)
    #pragma unroll
    for (int j = 0; j < 4; ++j) {
      const int qi = qb * 16 + g4 * 4 + j;
      float mj = -1e30f;
      #pragma unroll
      for (int cb = 0; cb < 12; ++cb) {
        const int kj = cb * 16 + c0;
        float sv = sc[cb][j] * 0.125f;
        if (qi >= MEM && kj > qi) sv = -1e30f;
        sc[cb][j] = sv;
        mj = fmaxf(mj, sv);
      }
      #pragma unroll
      for (int msk = 1; msk <= 8; msk <<= 1) mj = fmaxf(mj, __shfl_xor(mj, msk, 64));
      float sum = 0.f;
      #pragma unroll
      for (int cb = 0; cb < 12; ++cb) {
        const float p = exp2f((sc[cb][j] - mj) * 1.44269504f);
        sc[cb][j] = p;
        sum += p;
      }
      #pragma unroll
      for (int msk = 1; msk <= 8; msk <<= 1) sum += __shfl_xor(sum, msk, 64);
      const float rin = 1.0f / sum;
      #pragma unroll
      for (int cb = 0; cb < 12; ++cb)
        Pl[wid][(g4 * 4 + j) * 200 + cb * 16 + c0] = f2bf(sc[cb][j] * rin);
    }
    // PV: O[q][hd] = sum_k P[q][k] V[k][hd]
    #pragma unroll
    for (int cb2 = 0; cb2 < 4; ++cb2) {
      f32x4 ao = {};
      const int hd = cb2 * 16 + c0;
      #pragma unroll
      for (int kk = 0; kk < 6; ++kk) {
        const int k0 = kk * 32 + g4 * 8;
        const s16x8 pf = *reinterpret_cast<const s16x8*>(&Pl[wid][c0 * 200 + k0]);
        const s16x8 vf = *reinterpret_cast<const s16x8*>(&Vt[hd * 192 + (((k0 >> 3) + hd) % 24) * 8]);
        ao = __builtin_amdgcn_mfma_f32_16x16x32_bf16(pf, vf, ao, 0, 0, 0);
      }
      #pragma unroll
      for (int j = 0; j < 4; ++j) {
        const int q = qb * 16 + g4 * 4 + j;
        attno[((size_t)b * T + q) * D + h * 64 + cb2 * 16 + c0] = f2bf(ao[j]);
      }
    }
  }
}

} // namespace

extern "C" void kernel_launch(void* const* d_in, const int* in_sizes, int n_in,
                              void* d_out, int out_size, void* d_ws, size_t ws_size,
                              hipStream_t stream)
{
  const int*   ipr      = (const int*)d_in[0];
  const int*   isk      = (const int*)d_in[1];
  const float* embP     = (const float*)d_in[2];
  const float* embS     = (const float*)d_in[3];
  const float* mem_init = (const float*)d_in[4];
  const float* pos      = (const float*)d_in[5];
  const float* wqkv     = (const float*)d_in[6];
  const float* bqkv     = (const float*)d_in[7];
  const float* wo       = (const float*)d_in[8];
  const float* bo       = (const float*)d_in[9];
  const float* w1       = (const float*)d_in[10];
  const float* b1       = (const float*)d_in[11];
  const float* w2       = (const float*)d_in[12];
  const float* b2       = (const float*)d_in[13];
  const float* ln_a_g   = (const float*)d_in[14];
  const float* ln_a_b   = (const float*)d_in[15];
  const float* ln_f_g   = (const float*)d_in[16];
  const float* ln_f_b   = (const float*)d_in[17];
  const float* gw       = (const float*)d_in[18];
  const float* gb       = (const float*)d_in[19];
  float* out = (float*)d_out;
  (void)in_sizes; (void)n_in; (void)out_size; (void)ws_size;

  char* ws = (char*)d_ws;
  size_t off = 0;
  auto alloc = [&](size_t bytes) -> void* {
    void* p = ws + off; off += (bytes + 255) & ~(size_t)255; return p;
  };
  unsigned short* wqkv_b = (unsigned short*)alloc((size_t)3072 * 1024 * 2);
  unsigned short* wo_b   = (unsigned short*)alloc((size_t)1024 * 1024 * 2);
  unsigned short* w1_b   = (unsigned short*)alloc((size_t)4096 * 1024 * 2);
  unsigned short* w2_b   = (unsigned short*)alloc((size_t)1024 * 4096 * 2);
  unsigned short* gw_b   = (unsigned short*)alloc((size_t)1024 * 1024 * 2);
  float*          z      = (float*)alloc((size_t)B * T * D * 4);
  unsigned short* lnb    = (unsigned short*)alloc((size_t)B * T * D * 2);
  unsigned short* atno   = (unsigned short*)alloc((size_t)B * T * D * 2);
  unsigned short* big    = (unsigned short*)alloc((size_t)B * T * 4096 * 2); // qkv then ffn1
  unsigned short* candb  = (unsigned short*)alloc((size_t)B * MEM * D * 2);
  float*          memb   = (float*)alloc((size_t)B * MEM * D * 4);

  k_cvt<<<(3072 * 1024) / 256, 256, 0, stream>>>(wqkv, wqkv_b, 3072 * 1024);
  k_cvt<<<(1024 * 1024) / 256, 256, 0, stream>>>(wo,   wo_b,   1024 * 1024);
  k_cvt<<<(4096 * 1024) / 256, 256, 0, stream>>>(w1,   w1_b,   4096 * 1024);
  k_cvt<<<(1024 * 4096) / 256, 256, 0, stream>>>(w2,   w2_b,   1024 * 4096);
  k_cvt<<<(1024 * 1024) / 256, 256, 0, stream>>>(gw,   gw_b,   1024 * 1024);

  for (int t = 0; t < NC; ++t) {
    k_ln<0><<<B * T, 256, 0, stream>>>(memb, mem_init, pos, embP, embS, ipr, isk,
                                       ln_a_g, ln_a_b, z, lnb, t);
    { GArgs a{lnb, wqkv_b, bqkv, big, nullptr, nullptr, nullptr, nullptr, B * T, 3072, 1024, t};
      k_gemm<0><<<dim3(3072 / 128, (B * T) / 128), 256, 0, stream>>>(a); }
    k_attn<<<B * H, 256, 0, stream>>>(big, atno);
    { GArgs a{atno, wo_b, bo, nullptr, z, nullptr, nullptr, nullptr, B * T, 1024, 1024, t};
      k_gemm<2><<<dim3(1024 / 128, (B * T) / 128), 256, 0, stream>>>(a); }
    k_ln<1><<<B * T, 256, 0, stream>>>(nullptr, nullptr, nullptr, nullptr, nullptr,
                                       nullptr, nullptr, ln_f_g, ln_f_b, z, lnb, t);
    { GArgs a{lnb, w1_b, b1, big, nullptr, nullptr, nullptr, nullptr, B * T, 4096, 1024, t};
      k_gemm<1><<<dim3(4096 / 128, (B * T) / 128), 256, 0, stream>>>(a); }
    { GArgs a{big, w2_b, b2, nullptr, z, out, candb, nullptr, B * T, 1024, 4096, t};
      k_gemm<3><<<dim3(1024 / 128, (B * T) / 128), 256, 0, stream>>>(a); }
    { GArgs a{candb, gw_b, gb, nullptr, z, nullptr, nullptr, memb, B * MEM, 1024, 1024, t};
      k_gemm<4><<<dim3(1024 / 128, (B * MEM) / 128), 256, 0, stream>>>(a); }
  }
  k_copy_mem<<<(B * MEM * D) / 256, 256, 0, stream>>>(memb, out + (size_t)B * L * D);
}